// Round 10
// baseline (350.005 us; speedup 1.0000x reference)
//
#include <hip/hip_runtime.h>
#include <math.h>

// Problem constants (B=2, S=2048, D=1024, R=224)
#define D_DIM 1024
#define R_DIM 224
#define N_TOK 4096
#define KSPLIT 4
#define KRANGE (D_DIM / KSPLIT)        // 256
#define MCHUNK 32
#define NTHREADS 448                   // 7 waves; wave w owns cols [32w,32w+32)
#define COL_GRID (R_DIM * KSPLIT)      // 896
#define ROW_MBLK (N_TOK / MCHUNK)      // 128
#define ROW_GRID (ROW_MBLK * KSPLIT)   // 512
#define GRID2 (COL_GRID + ROW_GRID)    // 1408
#define L_FLOATS (N_TOK * R_DIM)       // 917504 per partial buffer

typedef short bf16x8 __attribute__((ext_vector_type(8)));
typedef short short8_t __attribute__((ext_vector_type(8)));
typedef float floatx4 __attribute__((ext_vector_type(4)));

__device__ __forceinline__ short f2bf(float f) {
    unsigned u = __float_as_uint(f);
    u += 0x7fffu + ((u >> 16) & 1u);   // round-to-nearest-even
    return (short)(u >> 16);
}

// ---------------------------------------------------------------------------
// Kernel 1: counting-sort tokens by row id (parallel scan); zero out[0].
// (No logits zeroing needed: every partial-L slot has exactly one writer.)
// ---------------------------------------------------------------------------
__global__ __launch_bounds__(1024) void init_kernel(
    const int* __restrict__ rid, int* __restrict__ sorted,
    int* __restrict__ cnt, int* __restrict__ off, float* __restrict__ out)
{
    const int tid = threadIdx.x;
    __shared__ int h[256];
    __shared__ int sc[2][256];
    __shared__ int cur[R_DIM];
    if (tid < 256) h[tid] = 0;
    __syncthreads();
    for (int n = tid; n < N_TOK; n += 1024) atomicAdd(&h[rid[n]], 1);
    __syncthreads();
    if (tid < 256) sc[0][tid] = h[tid];
    __syncthreads();
    int src = 0;
    for (int d = 1; d < 256; d <<= 1) {      // Hillis-Steele inclusive scan
        if (tid < 256) {
            int v = sc[src][tid];
            if (tid >= d) v += sc[src][tid - d];
            sc[src ^ 1][tid] = v;
        }
        __syncthreads();
        src ^= 1;
    }
    if (tid < R_DIM) {
        int o = sc[src][tid] - h[tid];       // exclusive
        off[tid] = o;
        cnt[tid] = h[tid];
        cur[tid] = o;
    }
    if (tid == 0) out[0] = 0.0f;
    __syncthreads();
    for (int n = tid; n < N_TOK; n += 1024) {
        int p = atomicAdd(&cur[rid[n]], 1);
        sorted[p] = n;
    }
}

// ---------------------------------------------------------------------------
// Kernel 2: partial GEMMs -> plain stores into per-ksplit logits buffers.
// Blocks [0, 896): col GEMM for (rho = bid>>2, ksplit = bid&3).
// Blocks [896, 1408): row GEMM for (mblk = idx>>2, ksplit = idx&3).
// A (<=32 tokens x 256 K) staged once in LDS as bf16 (XOR-swizzled rows);
// B (W slice) loaded straight to registers inside a barrier-free K-loop.
// mfma_f32_16x16x32_bf16 layouts (m89-verified):
//   a[j]=A[l&15][(l>>4)*8+j]; b[j]=B[(l>>4)*8+j][l&15]; acc r -> C[(l>>4)*4+r][l&15]
// ---------------------------------------------------------------------------
__global__ __launch_bounds__(NTHREADS) void gemm_kernel(
    const float* __restrict__ hs, const float* __restrict__ w_row,
    const float* __restrict__ w_col, const int* __restrict__ sorted,
    const int* __restrict__ cnt, const int* __restrict__ off,
    float* __restrict__ Lrow_p, float* __restrict__ Lcol_p)
{
    __shared__ short A_sh[MCHUNK * KRANGE];   // 16 KB, rows of 512 B, swizzled
    __shared__ int tok_sh[MCHUNK];

    const int bid = blockIdx.x;
    const int tid = threadIdx.x;
    const int lane = tid & 63;
    const int wv = tid >> 6;          // 0..6
    const int lm = lane & 15;
    const int lg = lane >> 4;         // 0..3

    const bool is_row = (bid >= COL_GRID);
    int ksp, tokbase, n_tok;
    const float* W;
    float* Ldst;
    if (is_row) {
        int idx = bid - COL_GRID;
        ksp = idx & 3;
        tokbase = (idx >> 2) * MCHUNK;
        n_tok = MCHUNK;
        W = w_row;
        Ldst = Lrow_p + (size_t)ksp * L_FLOATS;
    } else {
        int rho = bid >> 2;
        ksp = bid & 3;
        tokbase = off[rho];
        n_tok = cnt[rho];
        W = w_col + (size_t)rho * D_DIM * R_DIM;
        Ldst = Lcol_p + (size_t)ksp * L_FLOATS;
    }
    const int K0 = ksp * KRANGE;
    char* const Abp = (char*)A_sh;
    const int col0 = wv * 32 + lm;    // frag nt at col0 + nt*16

    const int n_chunks = (n_tok + MCHUNK - 1) / MCHUNK;
    for (int p = 0; p < n_chunks; ++p) {
        __syncthreads();              // prev chunk's A/tok reads complete
        if (tid < MCHUNK) {
            int gi = p * MCHUNK + tid;
            tok_sh[tid] = (gi < n_tok)
                ? (is_row ? (tokbase + gi) : sorted[tokbase + gi]) : -1;
        }
        __syncthreads();
        // ---- stage A once: 32 rows x 256 K, 16B writes, swizzled ----
        for (int i = tid; i < MCHUNK * (KRANGE / 8); i += NTHREADS) {
            int row = i >> 5;         // 32 8-elem groups per row
            int g8 = i & 31;
            int tok = tok_sh[row];
            float4 h0 = make_float4(0.f, 0.f, 0.f, 0.f);
            float4 h1 = make_float4(0.f, 0.f, 0.f, 0.f);
            if (tok >= 0) {
                const float* hp = &hs[(size_t)tok * D_DIM + K0 + g8 * 8];
                h0 = *reinterpret_cast<const float4*>(hp);
                h1 = *reinterpret_cast<const float4*>(hp + 4);
            }
            short8_t v = { f2bf(h0.x), f2bf(h0.y), f2bf(h0.z), f2bf(h0.w),
                           f2bf(h1.x), f2bf(h1.y), f2bf(h1.z), f2bf(h1.w) };
            *reinterpret_cast<short8_t*>(
                Abp + row * 512 + ((g8 * 16) ^ ((row & 7) << 4))) = v;
        }
        __syncthreads();

        // ---- barrier-free K loop: 8 steps of K=32 ----
        floatx4 acc[2][2];
#pragma unroll
        for (int ms = 0; ms < 2; ++ms)
#pragma unroll
            for (int nt = 0; nt < 2; ++nt) acc[ms][nt] = (floatx4)0.0f;

        for (int ks = 0; ks < 8; ++ks) {
            const float* bp = W + (size_t)(K0 + ks * 32 + lg * 8) * R_DIM + col0;
            float braw0[8], braw1[8];
#pragma unroll
            for (int j = 0; j < 8; ++j) braw0[j] = bp[j * R_DIM];
#pragma unroll
            for (int j = 0; j < 8; ++j) braw1[j] = bp[j * R_DIM + 16];
            bf16x8 bf0 = { f2bf(braw0[0]), f2bf(braw0[1]), f2bf(braw0[2]), f2bf(braw0[3]),
                           f2bf(braw0[4]), f2bf(braw0[5]), f2bf(braw0[6]), f2bf(braw0[7]) };
            bf16x8 bf1 = { f2bf(braw1[0]), f2bf(braw1[1]), f2bf(braw1[2]), f2bf(braw1[3]),
                           f2bf(braw1[4]), f2bf(braw1[5]), f2bf(braw1[6]), f2bf(braw1[7]) };
            const int kbyte = ks * 64 + lg * 16;
#pragma unroll
            for (int ms = 0; ms < 2; ++ms) {
                int row = ms * 16 + lm;
                bf16x8 a = *reinterpret_cast<const bf16x8*>(
                    Abp + row * 512 + (kbyte ^ ((row & 7) << 4)));
                acc[ms][0] = __builtin_amdgcn_mfma_f32_16x16x32_bf16(a, bf0, acc[ms][0], 0, 0, 0);
                acc[ms][1] = __builtin_amdgcn_mfma_f32_16x16x32_bf16(a, bf1, acc[ms][1], 0, 0, 0);
            }
        }

        // ---- epilogue: plain stores of partial logits (single writer/slot) ----
#pragma unroll
        for (int ms = 0; ms < 2; ++ms)
#pragma unroll
            for (int r = 0; r < 4; ++r) {
                int mloc = ms * 16 + lg * 4 + r;
                int tok = tok_sh[mloc];
                if (tok >= 0) {
                    Ldst[(size_t)tok * R_DIM + col0]      = acc[ms][0][r];
                    Ldst[(size_t)tok * R_DIM + col0 + 16] = acc[ms][1][r];
                }
            }
    }
}

// ---------------------------------------------------------------------------
// Kernel 3: per-token softmax + NLL; sums the 4 K-split partials per logit.
// One wave per token (grid-stride); block-reduced atomicAdd into out[0].
// ---------------------------------------------------------------------------
__global__ __launch_bounds__(256) void loss_kernel(
    const float* __restrict__ Lrow_p, const float* __restrict__ Lcol_p,
    const float* __restrict__ b_row, const float* __restrict__ b_col,
    const int* __restrict__ rid, const int* __restrict__ cid,
    float* __restrict__ out)
{
    __shared__ float wsum[4];
    const int tid = threadIdx.x;
    const int lane = tid & 63;
    const int wv = tid >> 6;
    const int gw = blockIdx.x * 4 + wv;      // 512 waves total
    float accum = 0.0f;

    for (int n = gw; n < N_TOK; n += 512) {
        const int rt = rid[n];
        const int ct = cid[n];
#pragma unroll
        for (int part = 0; part < 2; ++part) {
            const float* Lbase = (part == 0 ? Lrow_p : Lcol_p) + (size_t)n * R_DIM;
            const float* bp = (part == 0) ? b_row : (b_col + (size_t)rt * R_DIM);
            const int tgt = (part == 0) ? rt : ct;
            float v0 = 0.f, v1 = 0.f, v2 = 0.f, v3s = 0.f, vt = 0.f;
#pragma unroll
            for (int ksp = 0; ksp < KSPLIT; ++ksp) {
                const float* Lp = Lbase + (size_t)ksp * L_FLOATS;
                v0 += Lp[lane];
                v1 += Lp[lane + 64];
                v2 += Lp[lane + 128];
                if (lane < 32) v3s += Lp[lane + 192];
                vt += Lp[tgt];               // broadcast read
            }
            v0 += bp[lane];
            v1 += bp[lane + 64];
            v2 += bp[lane + 128];
            float v3 = (lane < 32) ? (v3s + bp[lane + 192]) : -1e30f;
            float m = fmaxf(fmaxf(v0, v1), fmaxf(v2, v3));
#pragma unroll
            for (int s = 32; s; s >>= 1) m = fmaxf(m, __shfl_xor(m, s));
            float sum = __expf(v0 - m) + __expf(v1 - m) + __expf(v2 - m)
                      + ((lane < 32) ? __expf(v3 - m) : 0.0f);
#pragma unroll
            for (int s = 32; s; s >>= 1) sum += __shfl_xor(sum, s);
            float tl = vt + bp[tgt];
            accum += -(tl - m - __logf(sum));
        }
    }
    if (lane == 0) wsum[wv] = accum;
    __syncthreads();
    if (tid == 0)
        atomicAdd(out, (wsum[0] + wsum[1] + wsum[2] + wsum[3]) * (1.0f / N_TOK));
}

extern "C" void kernel_launch(void* const* d_in, const int* in_sizes, int n_in,
                              void* d_out, int out_size, void* d_ws, size_t ws_size,
                              hipStream_t stream)
{
    const float* hs    = (const float*)d_in[0];   // [2,2048,1024]
    const float* w_row = (const float*)d_in[1];   // [1024,224]
    const float* b_row = (const float*)d_in[2];   // [224]
    const float* w_col = (const float*)d_in[3];   // [224,1024,224]
    const float* b_col = (const float*)d_in[4];   // [224,224]
    const int* rid     = (const int*)d_in[5];     // [2,2048]
    const int* cid     = (const int*)d_in[6];     // [2,2048]
    float* out = (float*)d_out;

    // ws: Lrow_p[4][4096*224], Lcol_p[4][4096*224], sorted, cnt, off  (~29.4MB)
    float* Lrow_p = (float*)d_ws;
    float* Lcol_p = Lrow_p + (size_t)KSPLIT * L_FLOATS;
    int* sorted = (int*)(Lcol_p + (size_t)KSPLIT * L_FLOATS);
    int* cnt    = sorted + N_TOK;
    int* off    = cnt + R_DIM;

    hipLaunchKernelGGL(init_kernel, dim3(1), dim3(1024), 0, stream,
                       rid, sorted, cnt, off, out);
    hipLaunchKernelGGL(gemm_kernel, dim3(GRID2), dim3(NTHREADS), 0, stream,
                       hs, w_row, w_col, sorted, cnt, off, Lrow_p, Lcol_p);
    hipLaunchKernelGGL(loss_kernel, dim3(128), dim3(256), 0, stream,
                       Lrow_p, Lcol_p, b_row, b_col, rid, cid, out);
}